// Round 1
// baseline (28644.498 us; speedup 1.0000x reference)
//
#include <hip/hip_runtime.h>

#define T_SEQ 512
#define BATCH 64
#define DIN0  512
#define D_H   1024
#define D_OUT 512
#define NBLK  256

typedef __attribute__((ext_vector_type(8))) short short8;
typedef __attribute__((ext_vector_type(4))) float f32x4;

__device__ inline float bf2f(unsigned short u) {
    unsigned x = ((unsigned)u) << 16;
    return __builtin_bit_cast(float, x);
}
__device__ inline unsigned short f2bf(float f) {
    unsigned x = __builtin_bit_cast(unsigned, f);
    unsigned r = (x + 0x7fffu + ((x >> 16) & 1u)) >> 16;
    return (unsigned short)r;
}
__device__ inline float fast_sigmoid(float x) {
    return 1.f / (1.f + __expf(-x));
}
__device__ inline float fast_tanh(float x) {
    float ax = fabsf(x);
    float t = __expf(-2.f * ax);
    float r = (1.f - t) / (1.f + t);
    return copysignf(r, x);
}

// ---------------- cast fp32 -> bf16 ----------------
__global__ void cast_kernel(const float* __restrict__ in, unsigned short* __restrict__ out, int n4) {
    int i = blockIdx.x * blockDim.x + threadIdx.x;
    int stride = gridDim.x * blockDim.x;
    for (; i < n4; i += stride) {
        float4 v = ((const float4*)in)[i];
        ushort4 o;
        o.x = f2bf(v.x); o.y = f2bf(v.y); o.z = f2bf(v.z); o.w = f2bf(v.w);
        ((ushort4*)out)[i] = o;
    }
}

// ---------------- grid barrier (persistent scan) ----------------
__device__ inline void grid_barrier(int* cnt, int* go, int nblk, int phase) {
    if (threadIdx.x == 0) {
        __threadfence();  // release: make h stores device-visible
        int prev = __hip_atomic_fetch_add(cnt, 1, __ATOMIC_ACQ_REL, __HIP_MEMORY_SCOPE_AGENT);
        if (prev == nblk - 1) {
            __hip_atomic_store(cnt, 0, __ATOMIC_RELAXED, __HIP_MEMORY_SCOPE_AGENT);
            __hip_atomic_store(go, phase, __ATOMIC_RELEASE, __HIP_MEMORY_SCOPE_AGENT);
        } else {
            while (__hip_atomic_load(go, __ATOMIC_RELAXED, __HIP_MEMORY_SCOPE_AGENT) < phase) {
                __builtin_amdgcn_s_sleep(1);
            }
        }
        __threadfence();  // acquire: invalidate caches so fresh h is observed
    }
    // single-wave block: lanes reconverge here
}

// ---------------- GRU layer scan ----------------
// grid = 256 blocks x 64 threads (1 wave). Block (rg,cb): batch rows rg*16..+16,
// h-cols cb*16..+16. n-gate weights (hn + xn) in LDS; r/z weights streamed from L2.
template <int DIN>
__global__ __launch_bounds__(64) void gru_scan(
    const unsigned short* __restrict__ xseq,  // [T][B][DIN] bf16
    const unsigned short* __restrict__ wih,   // [3H][DIN] bf16
    const unsigned short* __restrict__ whh,   // [3H][H]  bf16
    const float* __restrict__ bih, const float* __restrict__ bhh,
    const float* __restrict__ h0,             // [B][H] fp32 initial state
    float* __restrict__ hbuf_f,               // [2][B][H] fp32
    unsigned short* __restrict__ hbuf_b,      // [2][B][H] bf16
    unsigned short* __restrict__ Y,           // [T][B][H] bf16 output
    int* bar_cnt, int* bar_go, int phase_base, int nblk)
{
    __shared__ unsigned short lds[16 * (D_H + DIN)];  // [col][k] swizzled; <=64KB

    const int tid  = threadIdx.x;
    const int bid  = blockIdx.x;
    // map so the 4 row-groups of a col-block stay on the same XCD pair
    const int rg   = (bid & 7) >> 1;              // 0..3
    const int cb   = ((bid >> 3) << 1) | (bid & 1); // 0..63
    const int c0   = cb * 16, r0 = rg * 16;
    const int lane = tid;

    // ---- stage n-gate weights into LDS (once) ----
    for (int i = tid; i < 16 * (D_H / 8); i += 64) {
        int c = i / (D_H / 8), kb = i % (D_H / 8);
        int idx = (c * D_H + kb * 8) ^ ((c & 7) << 3);
        *(short8*)&lds[idx] = *(const short8*)&whh[(2 * D_H + c0 + c) * D_H + kb * 8];
    }
    for (int i = tid; i < 16 * (DIN / 8); i += 64) {
        int c = i / (DIN / 8), kb = i % (DIN / 8);
        int idx = 16 * D_H + ((c * DIN + kb * 8) ^ ((c & 7) << 3));
        *(short8*)&lds[idx] = *(const short8*)&wih[(2 * D_H + c0 + c) * DIN + kb * 8];
    }

    // ---- init h[0] (each block its own 16x16 tile) ----
    for (int i = tid; i < 256; i += 64) {
        int rr = r0 + (i >> 4), cc = c0 + (i & 15);
        float v = h0[rr * D_H + cc];
        hbuf_f[rr * D_H + cc] = v;
        hbuf_b[rr * D_H + cc] = f2bf(v);
    }
    int phase = phase_base + 1;
    grid_barrier(bar_cnt, bar_go, nblk, phase);

    // per-lane column + biases (col = lane&15)
    const int gc = c0 + (lane & 15);
    const float b_r  = bih[gc] + bhh[gc];
    const float b_z  = bih[D_H + gc] + bhh[D_H + gc];
    const float b_xn = bih[2 * D_H + gc];
    const float b_hn = bhh[2 * D_H + gc];

    const int arow = lane & 15, ako = (lane >> 4) * 8;   // A-frag lane mapping
    const int bcol = lane & 15, bko = (lane >> 4) * 8;   // B-frag lane mapping

    for (int t = 0; t < T_SEQ; ++t) {
        const int cur = t & 1, nxt = cur ^ 1;
        const unsigned short* hb = hbuf_b + cur * (BATCH * D_H);
        const unsigned short* xt = xseq + (size_t)t * (BATCH * DIN);

        f32x4 fr = {0.f,0.f,0.f,0.f}, fz = fr, fnh = fr, fnx = fr;

        // h-side: K = 1024
        #pragma unroll 4
        for (int k = 0; k < D_H; k += 32) {
            short8 a = *(const short8*)&hb[(r0 + arow) * D_H + k + ako];
            short8 br = *(const short8*)&whh[(c0 + bcol) * D_H + k + bko];
            short8 bz = *(const short8*)&whh[(D_H + c0 + bcol) * D_H + k + bko];
            int nidx = ((bcol * D_H + k + bko) ^ ((bcol & 7) << 3));
            short8 bn = *(const short8*)&lds[nidx];
            fr  = __builtin_amdgcn_mfma_f32_16x16x32_bf16(a, br, fr, 0, 0, 0);
            fz  = __builtin_amdgcn_mfma_f32_16x16x32_bf16(a, bz, fz, 0, 0, 0);
            fnh = __builtin_amdgcn_mfma_f32_16x16x32_bf16(a, bn, fnh, 0, 0, 0);
        }
        // x-side: K = DIN
        #pragma unroll 4
        for (int k = 0; k < DIN; k += 32) {
            short8 a = *(const short8*)&xt[(r0 + arow) * DIN + k + ako];
            short8 br = *(const short8*)&wih[(c0 + bcol) * DIN + k + bko];
            short8 bz = *(const short8*)&wih[(D_H + c0 + bcol) * DIN + k + bko];
            int nidx = 16 * D_H + ((bcol * DIN + k + bko) ^ ((bcol & 7) << 3));
            short8 bn = *(const short8*)&lds[nidx];
            fr  = __builtin_amdgcn_mfma_f32_16x16x32_bf16(a, br, fr, 0, 0, 0);
            fz  = __builtin_amdgcn_mfma_f32_16x16x32_bf16(a, bz, fz, 0, 0, 0);
            fnx = __builtin_amdgcn_mfma_f32_16x16x32_bf16(a, bn, fnx, 0, 0, 0);
        }

        // epilogue: gates + state update (C layout: col=lane&15, row=(lane>>4)*4+i)
        float* hf_n = hbuf_f + nxt * (BATCH * D_H);
        const float* hf_c = hbuf_f + cur * (BATCH * D_H);
        unsigned short* hb_n = hbuf_b + nxt * (BATCH * D_H);
        unsigned short* yt = Y + (size_t)t * (BATCH * D_H);
        #pragma unroll
        for (int i = 0; i < 4; ++i) {
            int rr = r0 + (lane >> 4) * 4 + i;
            float r = fast_sigmoid(fr[i] + b_r);
            float z = fast_sigmoid(fz[i] + b_z);
            float n = fast_tanh(fnx[i] + b_xn + r * (fnh[i] + b_hn));
            float hp = hf_c[rr * D_H + gc];
            float hn = (1.f - z) * n + z * hp;
            hf_n[rr * D_H + gc] = hn;
            unsigned short hnb = f2bf(hn);
            hb_n[rr * D_H + gc] = hnb;
            yt[rr * D_H + gc] = hnb;
        }

        ++phase;
        grid_barrier(bar_cnt, bar_go, nblk, phase);
    }
}

// ---------------- fused LayerNorm + output projection ----------------
// grid = 2048 blocks x 256 threads; each block: 16 rows of [32768][1024]
__global__ __launch_bounds__(256) void ln_proj(
    const unsigned short* __restrict__ y1,   // [TB][1024] bf16
    const float* __restrict__ gamma, const float* __restrict__ beta,
    const unsigned short* __restrict__ ffw,  // [512][1024] bf16
    const float* __restrict__ ffb,           // [512]
    float* __restrict__ out)                 // [TB][512]
{
    __shared__ unsigned short ylds[16 * 1024];  // 32KB, swizzled
    const int row0 = blockIdx.x * 16;
    const int tid = threadIdx.x;

    // ---- LayerNorm: 16 threads per row ----
    {
        const int rr = tid >> 4, l16 = tid & 15;
        const unsigned short* yrow = y1 + (size_t)(row0 + rr) * D_H;
        float s = 0.f, sq = 0.f;
        #pragma unroll
        for (int j8 = 0; j8 < 8; ++j8) {
            int k = l16 * 64 + j8 * 8;
            short8 v = *(const short8*)&yrow[k];
            int idx = (rr * 1024 + k) ^ ((rr & 7) << 3);
            *(short8*)&ylds[idx] = v;
            #pragma unroll
            for (int j = 0; j < 8; ++j) {
                float f = bf2f((unsigned short)v[j]);
                s += f; sq += f * f;
            }
        }
        #pragma unroll
        for (int o = 1; o < 16; o <<= 1) {
            s  += __shfl_xor(s, o, 64);
            sq += __shfl_xor(sq, o, 64);
        }
        float mu = s * (1.f / 1024.f);
        float var = sq * (1.f / 1024.f) - mu * mu;
        float rstd = rsqrtf(var + 1e-5f);
        #pragma unroll
        for (int j8 = 0; j8 < 8; ++j8) {
            int k = l16 * 64 + j8 * 8;
            int idx = (rr * 1024 + k) ^ ((rr & 7) << 3);
            short8 v = *(short8*)&ylds[idx];
            short8 o8;
            #pragma unroll
            for (int j = 0; j < 8; ++j) {
                float f = bf2f((unsigned short)v[j]);
                f = (f - mu) * rstd * gamma[k + j] + beta[k + j];
                o8[j] = (short)f2bf(f);
            }
            *(short8*)&ylds[idx] = o8;
        }
    }
    __syncthreads();

    // ---- GEMM: 16 x 512, K=1024; 4 waves x 128 cols ----
    const int w = tid >> 6, lane = tid & 63;
    const int cbase = w * 128;
    const int arow = lane & 15, ako = (lane >> 4) * 8;
    f32x4 acc[8] = {};
    for (int k = 0; k < D_H; k += 32) {
        int aidx = (arow * 1024 + k + ako) ^ ((arow & 7) << 3);
        short8 a = *(const short8*)&ylds[aidx];
        #pragma unroll
        for (int n = 0; n < 8; ++n) {
            int col = cbase + n * 16 + (lane & 15);
            short8 b = *(const short8*)&ffw[col * 1024 + k + ako];
            acc[n] = __builtin_amdgcn_mfma_f32_16x16x32_bf16(a, b, acc[n], 0, 0, 0);
        }
    }
    #pragma unroll
    for (int n = 0; n < 8; ++n) {
        int col = cbase + n * 16 + (lane & 15);
        float bb = ffb[col];
        #pragma unroll
        for (int i = 0; i < 4; ++i) {
            int rr = row0 + (lane >> 4) * 4 + i;
            out[(size_t)rr * D_OUT + col] = acc[n][i] + bb;
        }
    }
}

// ---------------- launch ----------------
extern "C" void kernel_launch(void* const* d_in, const int* in_sizes, int n_in,
                              void* d_out, int out_size, void* d_ws, size_t ws_size,
                              hipStream_t stream) {
    const float* x     = (const float*)d_in[0];
    const float* h     = (const float*)d_in[1];
    const float* w_ih0 = (const float*)d_in[2];
    const float* w_hh0 = (const float*)d_in[3];
    const float* b_ih0 = (const float*)d_in[4];
    const float* b_hh0 = (const float*)d_in[5];
    const float* w_ih1 = (const float*)d_in[6];
    const float* w_hh1 = (const float*)d_in[7];
    const float* b_ih1 = (const float*)d_in[8];
    const float* b_hh1 = (const float*)d_in[9];
    const float* ln_g  = (const float*)d_in[10];
    const float* ln_b  = (const float*)d_in[11];
    const float* ff_w  = (const float*)d_in[12];
    const float* ff_b  = (const float*)d_in[13];
    float* out = (float*)d_out;

    char* ws = (char*)d_ws;
    size_t off = 0;
    auto alloc = [&](size_t bytes) {
        void* p = ws + off;
        off = (off + bytes + 255) & ~(size_t)255;
        return p;
    };
    unsigned short* x_bf   = (unsigned short*)alloc((size_t)T_SEQ * BATCH * DIN0 * 2);
    unsigned short* y1_bf  = (unsigned short*)alloc((size_t)T_SEQ * BATCH * D_H * 2);
    unsigned short* wih0_b = (unsigned short*)alloc((size_t)3 * D_H * DIN0 * 2);
    unsigned short* whh0_b = (unsigned short*)alloc((size_t)3 * D_H * D_H * 2);
    unsigned short* wih1_b = (unsigned short*)alloc((size_t)3 * D_H * D_H * 2);
    unsigned short* whh1_b = (unsigned short*)alloc((size_t)3 * D_H * D_H * 2);
    unsigned short* ffw_b  = (unsigned short*)alloc((size_t)D_OUT * D_H * 2);
    float*          hbuf_f = (float*)alloc((size_t)2 * BATCH * D_H * 4);
    unsigned short* hbuf_b = (unsigned short*)alloc((size_t)2 * BATCH * D_H * 2);
    int*            bar    = (int*)alloc(256);
    if (off > ws_size) return;  // workspace too small: fail loudly (output stays poisoned)

    unsigned short* y0_bf = (unsigned short*)d_out;  // 67MB: exact fit, overwritten by ln_proj later

    hipMemsetAsync(bar, 0, 256, stream);

    auto castl = [&](const float* src, unsigned short* dst, int n) {
        int n4 = n / 4;
        int blocks = (n4 + 255) / 256;
        if (blocks > 2048) blocks = 2048;
        hipLaunchKernelGGL(cast_kernel, dim3(blocks), dim3(256), 0, stream, src, dst, n4);
    };
    castl(x,     x_bf,   T_SEQ * BATCH * DIN0);
    castl(w_ih0, wih0_b, 3 * D_H * DIN0);
    castl(w_hh0, whh0_b, 3 * D_H * D_H);
    castl(w_ih1, wih1_b, 3 * D_H * D_H);
    castl(w_hh1, whh1_b, 3 * D_H * D_H);
    castl(ff_w,  ffw_b,  D_OUT * D_H);

    hipLaunchKernelGGL((gru_scan<DIN0>), dim3(NBLK), dim3(64), 0, stream,
        x_bf, wih0_b, whh0_b, b_ih0, b_hh0, h, hbuf_f, hbuf_b, y0_bf,
        bar, bar + 32, 0, NBLK);
    hipLaunchKernelGGL((gru_scan<D_H>), dim3(NBLK), dim3(64), 0, stream,
        y0_bf, wih1_b, whh1_b, b_ih1, b_hh1, h + BATCH * D_H, hbuf_f, hbuf_b, y1_bf,
        bar, bar + 32, 1024, NBLK);
    hipLaunchKernelGGL(ln_proj, dim3(T_SEQ * BATCH / 16), dim3(256), 0, stream,
        y1_bf, ln_g, ln_b, ffw_b, ff_b, out);
}

// Round 2
// 13633.647 us; speedup vs baseline: 2.1010x; 2.1010x over previous
//
#include <hip/hip_runtime.h>

#define T_SEQ 512
#define BATCH 64
#define DIN0  512
#define D_H   1024
#define D_OUT 512
#define NBLK  256

typedef __attribute__((ext_vector_type(8))) short short8;
typedef __attribute__((ext_vector_type(4))) float f32x4;

__device__ inline float bf2f(unsigned short u) {
    unsigned x = ((unsigned)u) << 16;
    return __builtin_bit_cast(float, x);
}
__device__ inline unsigned short f2bf(float f) {
    unsigned x = __builtin_bit_cast(unsigned, f);
    unsigned r = (x + 0x7fffu + ((x >> 16) & 1u)) >> 16;
    return (unsigned short)r;
}
__device__ inline float fast_sigmoid(float x) { return 1.f / (1.f + __expf(-x)); }
__device__ inline float fast_tanh(float x) {
    float ax = fabsf(x);
    float t = __expf(-2.f * ax);
    float r = (1.f - t) / (1.f + t);
    return copysignf(r, x);
}

// global -> LDS async copy, coherent (sc0|sc1 = 1|16 = 17): reads at the
// coherence point (L3), never allocates into the (non-coherent) per-XCD L2.
__device__ inline void async_ld16_cohere(const void* g, void* l) {
    __builtin_amdgcn_global_load_lds((const __attribute__((address_space(1))) void*)g,
                                     (__attribute__((address_space(3))) void*)l,
                                     16, 0, 17);
}
// write-through bf16 store (visible device-wide once vmcnt==0, no L2 dirty line)
__device__ inline void store_u16_sc01(void* p, unsigned v) {
    asm volatile("global_store_short %0, %1, off sc0 sc1" :: "v"(p), "v"(v) : "memory");
}

// Relaxed grid barrier: monotonic counter (no reset race), no cache
// invalidation. Shared data (h) travels via sc0sc1 ops, so no fences needed.
__device__ inline void grid_barrier(int* cnt, int* go, int target_phase, int nblk) {
    if (threadIdx.x == 0) {
        asm volatile("s_waitcnt vmcnt(0)" ::: "memory");  // h stores at coherence point
        int prev = __hip_atomic_fetch_add(cnt, 1, __ATOMIC_RELAXED, __HIP_MEMORY_SCOPE_AGENT);
        if (prev == target_phase * nblk - 1) {
            __hip_atomic_store(go, target_phase, __ATOMIC_RELAXED, __HIP_MEMORY_SCOPE_AGENT);
        } else {
            while (__hip_atomic_load(go, __ATOMIC_RELAXED, __HIP_MEMORY_SCOPE_AGENT) < target_phase) {
                __builtin_amdgcn_s_sleep(1);
            }
        }
    }
    asm volatile("" ::: "memory");
}

// ---------------- cast fp32 -> bf16 ----------------
__global__ void cast_kernel(const float* __restrict__ in, unsigned short* __restrict__ out, int n4) {
    int i = blockIdx.x * blockDim.x + threadIdx.x;
    int stride = gridDim.x * blockDim.x;
    for (; i < n4; i += stride) {
        float4 v = ((const float4*)in)[i];
        ushort4 o;
        o.x = f2bf(v.x); o.y = f2bf(v.y); o.z = f2bf(v.z); o.w = f2bf(v.w);
        ((ushort4*)out)[i] = o;
    }
}

// ---------------- GRU layer scan ----------------
// 256 blocks x 64 threads. Block owns rows r0..r0+16 x cols c0..c0+16.
// LDS: n-gate + r-gate weights (full K = H+DIN) + 16x1024 h staging tile.
// z-gate weights streamed from L2 (cache never invalidated now).
template <int DIN>
__global__ __launch_bounds__(64, 1) void gru_scan(
    const unsigned short* __restrict__ xseq,  // [T][B][DIN] bf16
    const unsigned short* __restrict__ wih,   // [3H][DIN] bf16 (r,z,n)
    const unsigned short* __restrict__ whh,   // [3H][H]  bf16
    const float* __restrict__ bih, const float* __restrict__ bhh,
    const float* __restrict__ h0,             // [B][H] fp32
    unsigned short* __restrict__ hbuf,        // [2][B][H] bf16 (coherent exchange)
    unsigned short* __restrict__ Y,           // [T][B][H] bf16
    int* bar_cnt, int* bar_go, int phase_base, int nblk)
{
    extern __shared__ unsigned short lds[];
    constexpr int KT = D_H + DIN;             // per-gate K (h part then x part)
    // LDS layout (elements): Wn [16][KT] @0 ; Wr @16*KT ; stage [16][1024] @32*KT

    const int lane = threadIdx.x;
    const int bid  = blockIdx.x;
    // XCD-aware mapping: low 3 bits of bid = XCD (default round-robin dispatch).
    // Give each XCD 8 col-blocks x 4 row-groups so z-weights/x-slabs stay L2-local.
    const int xcd = bid & 7, slot = bid >> 3;
    const int cb  = xcd * 8 + (slot & 7);
    const int rg  = slot >> 3;
    const int c0  = cb * 16, r0 = rg * 16;

    // ---- stage n-gate and r-gate weights into LDS (once) ----
    for (int g = 0; g < 2; ++g) {
        const int grow = (g == 0) ? 2 * D_H : 0;   // g=0: n, g=1: r
        unsigned short* W = lds + g * 16 * KT;
        for (int i = lane; i < 16 * (D_H / 8); i += 64) {
            int c = i >> 7, kb = i & 127;
            int el = (c * KT + kb * 8) ^ ((c & 7) << 3);
            *(short8*)&W[el] = *(const short8*)&whh[(size_t)(grow + c0 + c) * D_H + kb * 8];
        }
        for (int i = lane; i < 16 * (DIN / 8); i += 64) {
            int c = i / (DIN / 8), kb = i % (DIN / 8);
            int el = (c * KT + D_H + kb * 8) ^ ((c & 7) << 3);
            *(short8*)&W[el] = *(const short8*)&wih[(size_t)(grow + c0 + c) * DIN + kb * 8];
        }
    }

    // ---- init h tile: fp32 state in registers, bf16 published via sc0sc1 ----
    const int gc   = c0 + (lane & 15);
    const int crow = (lane >> 4) * 4;
    float hprev[4];
    #pragma unroll
    for (int i = 0; i < 4; ++i) {
        float v = h0[(size_t)(r0 + crow + i) * D_H + gc];
        hprev[i] = v;
        store_u16_sc01(&hbuf[(size_t)(r0 + crow + i) * D_H + gc], (unsigned)f2bf(v));
    }
    grid_barrier(bar_cnt, bar_go, phase_base + 1, nblk);

    const float b_r  = bih[gc] + bhh[gc];
    const float b_z  = bih[D_H + gc] + bhh[D_H + gc];
    const float b_xn = bih[2 * D_H + gc];
    const float b_hn = bhh[2 * D_H + gc];

    const int arow = lane & 15;          // A row / B col for MFMA fragments
    const int ako  = (lane >> 4) * 8;    // k sub-offset
    unsigned short* stage = lds + 32 * KT;

    for (int t = 0; t < T_SEQ; ++t) {
        const unsigned short* hb  = hbuf + (t & 1) * (BATCH * D_H);
        unsigned short*       hbn = hbuf + ((t & 1) ^ 1) * (BATCH * D_H);
        const unsigned short* xt  = xseq + (size_t)t * BATCH * DIN;
        unsigned short*       Yt  = Y + (size_t)t * BATCH * D_H;

        // ---- issue coherent h-tile staging (16 rows x 1024), swizzled src ----
        #pragma unroll
        for (int i = 0; i < 32; ++i) {
            int row = i >> 1, hf = i & 1;
            int swz = row & 7;
            const unsigned short* src =
                hb + (size_t)(r0 + row) * D_H + (hf * 64 + (lane ^ swz)) * 8;
            async_ld16_cohere(src, &stage[row * 1024 + hf * 512]);
        }

        f32x4 fr = {0.f, 0.f, 0.f, 0.f}, fz = fr, fnx = fr, fnh = fr;

        // ---- x-side (overlaps h staging latency): A from cached global x ----
        #pragma unroll 4
        for (int k = 0; k < DIN; k += 32) {
            short8 a  = *(const short8*)&xt[(size_t)(r0 + arow) * DIN + k + ako];
            int el    = (arow * KT + D_H + k + ako) ^ ((arow & 7) << 3);
            short8 bn = *(const short8*)&lds[el];
            short8 br = *(const short8*)&lds[16 * KT + el];
            short8 bz = *(const short8*)&wih[(size_t)(D_H + c0 + arow) * DIN + k + ako];
            fr  = __builtin_amdgcn_mfma_f32_16x16x32_bf16(a, br, fr, 0, 0, 0);
            fz  = __builtin_amdgcn_mfma_f32_16x16x32_bf16(a, bz, fz, 0, 0, 0);
            fnx = __builtin_amdgcn_mfma_f32_16x16x32_bf16(a, bn, fnx, 0, 0, 0);
        }

        // ---- wait staging, then h-side: A from LDS stage ----
        asm volatile("s_waitcnt vmcnt(0)" ::: "memory");
        __builtin_amdgcn_sched_barrier(0);
        #pragma unroll 4
        for (int k = 0; k < D_H; k += 32) {
            int sel   = (arow * 1024 + k + ako) ^ ((arow & 7) << 3);
            short8 a  = *(const short8*)&stage[sel];
            int el    = (arow * KT + k + ako) ^ ((arow & 7) << 3);
            short8 bn = *(const short8*)&lds[el];
            short8 br = *(const short8*)&lds[16 * KT + el];
            short8 bz = *(const short8*)&whh[(size_t)(D_H + c0 + arow) * D_H + k + ako];
            fr  = __builtin_amdgcn_mfma_f32_16x16x32_bf16(a, br, fr, 0, 0, 0);
            fz  = __builtin_amdgcn_mfma_f32_16x16x32_bf16(a, bz, fz, 0, 0, 0);
            fnh = __builtin_amdgcn_mfma_f32_16x16x32_bf16(a, bn, fnh, 0, 0, 0);
        }

        // ---- epilogue: gates + state update; publish h via sc0sc1 ----
        #pragma unroll
        for (int i = 0; i < 4; ++i) {
            int rr = r0 + crow + i;
            float r = fast_sigmoid(fr[i] + b_r);
            float z = fast_sigmoid(fz[i] + b_z);
            float n = fast_tanh(fnx[i] + b_xn + r * (fnh[i] + b_hn));
            float hn = (1.f - z) * n + z * hprev[i];
            hprev[i] = hn;
            unsigned short h16 = f2bf(hn);
            store_u16_sc01(&hbn[(size_t)rr * D_H + gc], (unsigned)h16);
            Yt[(size_t)rr * D_H + gc] = h16;   // normal cached store
        }

        if (t < T_SEQ - 1)
            grid_barrier(bar_cnt, bar_go, phase_base + 2 + t, nblk);
    }
}

// ---------------- fused LayerNorm + output projection ----------------
__global__ __launch_bounds__(256) void ln_proj(
    const unsigned short* __restrict__ y1,   // [TB][1024] bf16
    const float* __restrict__ gamma, const float* __restrict__ beta,
    const unsigned short* __restrict__ ffw,  // [512][1024] bf16
    const float* __restrict__ ffb,           // [512]
    float* __restrict__ out)                 // [TB][512]
{
    __shared__ unsigned short ylds[16 * 1024];
    const int row0 = blockIdx.x * 16;
    const int tid = threadIdx.x;

    {
        const int rr = tid >> 4, l16 = tid & 15;
        const unsigned short* yrow = y1 + (size_t)(row0 + rr) * D_H;
        float s = 0.f, sq = 0.f;
        #pragma unroll
        for (int j8 = 0; j8 < 8; ++j8) {
            int k = l16 * 64 + j8 * 8;
            short8 v = *(const short8*)&yrow[k];
            int idx = (rr * 1024 + k) ^ ((rr & 7) << 3);
            *(short8*)&ylds[idx] = v;
            #pragma unroll
            for (int j = 0; j < 8; ++j) {
                float f = bf2f((unsigned short)v[j]);
                s += f; sq += f * f;
            }
        }
        #pragma unroll
        for (int o = 1; o < 16; o <<= 1) {
            s  += __shfl_xor(s, o, 64);
            sq += __shfl_xor(sq, o, 64);
        }
        float mu = s * (1.f / 1024.f);
        float var = sq * (1.f / 1024.f) - mu * mu;
        float rstd = rsqrtf(var + 1e-5f);
        #pragma unroll
        for (int j8 = 0; j8 < 8; ++j8) {
            int k = l16 * 64 + j8 * 8;
            int idx = (rr * 1024 + k) ^ ((rr & 7) << 3);
            short8 v = *(short8*)&ylds[idx];
            short8 o8;
            #pragma unroll
            for (int j = 0; j < 8; ++j) {
                float f = bf2f((unsigned short)v[j]);
                f = (f - mu) * rstd * gamma[k + j] + beta[k + j];
                o8[j] = (short)f2bf(f);
            }
            *(short8*)&ylds[idx] = o8;
        }
    }
    __syncthreads();

    const int w = tid >> 6, lane = tid & 63;
    const int cbase = w * 128;
    const int arow = lane & 15, ako = (lane >> 4) * 8;
    f32x4 acc[8] = {};
    for (int k = 0; k < D_H; k += 32) {
        int aidx = (arow * 1024 + k + ako) ^ ((arow & 7) << 3);
        short8 a = *(const short8*)&ylds[aidx];
        #pragma unroll
        for (int n = 0; n < 8; ++n) {
            int col = cbase + n * 16 + (lane & 15);
            short8 b = *(const short8*)&ffw[col * 1024 + k + ako];
            acc[n] = __builtin_amdgcn_mfma_f32_16x16x32_bf16(a, b, acc[n], 0, 0, 0);
        }
    }
    #pragma unroll
    for (int n = 0; n < 8; ++n) {
        int col = cbase + n * 16 + (lane & 15);
        float bb = ffb[col];
        #pragma unroll
        for (int i = 0; i < 4; ++i) {
            int rr = row0 + (lane >> 4) * 4 + i;
            out[(size_t)rr * D_OUT + col] = acc[n][i] + bb;
        }
    }
}

// ---------------- launch ----------------
extern "C" void kernel_launch(void* const* d_in, const int* in_sizes, int n_in,
                              void* d_out, int out_size, void* d_ws, size_t ws_size,
                              hipStream_t stream) {
    const float* x     = (const float*)d_in[0];
    const float* h     = (const float*)d_in[1];
    const float* w_ih0 = (const float*)d_in[2];
    const float* w_hh0 = (const float*)d_in[3];
    const float* b_ih0 = (const float*)d_in[4];
    const float* b_hh0 = (const float*)d_in[5];
    const float* w_ih1 = (const float*)d_in[6];
    const float* w_hh1 = (const float*)d_in[7];
    const float* b_ih1 = (const float*)d_in[8];
    const float* b_hh1 = (const float*)d_in[9];
    const float* ln_g  = (const float*)d_in[10];
    const float* ln_b  = (const float*)d_in[11];
    const float* ff_w  = (const float*)d_in[12];
    const float* ff_b  = (const float*)d_in[13];
    float* out = (float*)d_out;

    char* ws = (char*)d_ws;
    size_t off = 0;
    auto alloc = [&](size_t bytes) {
        void* p = ws + off;
        off = (off + bytes + 255) & ~(size_t)255;
        return p;
    };
    unsigned short* x_bf   = (unsigned short*)alloc((size_t)T_SEQ * BATCH * DIN0 * 2);
    unsigned short* y1_bf  = (unsigned short*)alloc((size_t)T_SEQ * BATCH * D_H * 2);
    unsigned short* wih0_b = (unsigned short*)alloc((size_t)3 * D_H * DIN0 * 2);
    unsigned short* whh0_b = (unsigned short*)alloc((size_t)3 * D_H * D_H * 2);
    unsigned short* wih1_b = (unsigned short*)alloc((size_t)3 * D_H * D_H * 2);
    unsigned short* whh1_b = (unsigned short*)alloc((size_t)3 * D_H * D_H * 2);
    unsigned short* ffw_b  = (unsigned short*)alloc((size_t)D_OUT * D_H * 2);
    unsigned short* hbuf   = (unsigned short*)alloc((size_t)2 * BATCH * D_H * 2);
    int*            bar    = (int*)alloc(256);
    if (off > ws_size) return;

    unsigned short* y0_bf = (unsigned short*)d_out;  // 67MB staging, overwritten by ln_proj

    hipMemsetAsync(bar, 0, 256, stream);

    auto castl = [&](const float* src, unsigned short* dst, int n) {
        int n4 = n / 4;
        int blocks = (n4 + 255) / 256;
        if (blocks > 2048) blocks = 2048;
        hipLaunchKernelGGL(cast_kernel, dim3(blocks), dim3(256), 0, stream, src, dst, n4);
    };
    castl(x,     x_bf,   T_SEQ * BATCH * DIN0);
    castl(w_ih0, wih0_b, 3 * D_H * DIN0);
    castl(w_hh0, whh0_b, 3 * D_H * D_H);
    castl(w_ih1, wih1_b, 3 * D_H * D_H);
    castl(w_hh1, whh1_b, 3 * D_H * D_H);
    castl(ff_w,  ffw_b,  D_OUT * D_H);

    const int lds0 = (32 * (D_H + DIN0) + 16 * 1024) * 2;   // 131072
    const int lds1 = (32 * (D_H + D_H) + 16 * 1024) * 2;    // 163840
    hipFuncSetAttribute((const void*)&gru_scan<DIN0>,
                        hipFuncAttributeMaxDynamicSharedMemorySize, lds0);
    hipFuncSetAttribute((const void*)&gru_scan<D_H>,
                        hipFuncAttributeMaxDynamicSharedMemorySize, lds1);

    hipLaunchKernelGGL((gru_scan<DIN0>), dim3(NBLK), dim3(64), lds0, stream,
        x_bf, wih0_b, whh0_b, b_ih0, b_hh0, h, hbuf, y0_bf,
        bar, bar + 32, 0, NBLK);
    hipLaunchKernelGGL((gru_scan<D_H>), dim3(NBLK), dim3(64), lds1, stream,
        y0_bf, wih1_b, whh1_b, b_ih1, b_hh1, h + BATCH * D_H, hbuf, y1_bf,
        bar, bar + 32, 512, NBLK);
    hipLaunchKernelGGL(ln_proj, dim3(T_SEQ * BATCH / 16), dim3(256), 0, stream,
        y1_bf, ln_g, ln_b, ffw_b, ff_b, out);
}

// Round 4
// 8311.655 us; speedup vs baseline: 3.4463x; 1.6403x over previous
//
#include <hip/hip_runtime.h>

#define T_SEQ 512
#define BATCH 64
#define DIN0  512
#define D_H   1024
#define D_OUT 512
#define NBLK  256

typedef __attribute__((ext_vector_type(8))) short short8;
typedef __attribute__((ext_vector_type(4))) float f32x4;

__device__ inline float bf2f(unsigned short u) {
    unsigned x = ((unsigned)u) << 16;
    return __builtin_bit_cast(float, x);
}
__device__ inline unsigned short f2bf(float f) {
    unsigned x = __builtin_bit_cast(unsigned, f);
    unsigned r = (x + 0x7fffu + ((x >> 16) & 1u)) >> 16;
    return (unsigned short)r;
}
__device__ inline float fast_sigmoid(float x) { return 1.f / (1.f + __expf(-x)); }
__device__ inline float fast_tanh(float x) {
    float ax = fabsf(x);
    float t = __expf(-2.f * ax);
    float r = (1.f - t) / (1.f + t);
    return copysignf(r, x);
}

// ---- coherence-point primitives (all proven in round 2) ----
// write-through bf16 store: device-visible once vmcnt==0, no L2 dirty line.
__device__ inline void store_u16_sc01(void* p, unsigned v) {
    asm volatile("global_store_short %0, %1, off sc0 sc1" :: "v"(p), "v"(v) : "memory");
}
__device__ inline void store_flag(int* p, int v) {
    asm volatile("global_store_dword %0, %1, off sc0 sc1" :: "v"(p), "v"(v) : "memory");
}
// coherence-point 4B load (poll); wait inside so each loop iter re-loads fresh.
__device__ inline int load_flag(const int* p) {
    int r;
    asm volatile("global_load_dword %0, %1, off sc0 sc1\n\ts_waitcnt vmcnt(0)"
                 : "=&v"(r) : "v"(p) : "memory");
    return r;
}
// coherence-point 16B load, NO wait (batched; caller waits vmcnt once).
__device__ inline short8 load16_sc01(const void* p) {
    short8 r;
    asm volatile("global_load_dwordx4 %0, %1, off sc0 sc1"
                 : "=&v"(r) : "v"(p) : "memory");
    return r;
}

// ---------------- cast fp32 -> bf16 ----------------
__global__ void cast_kernel(const float* __restrict__ in, unsigned short* __restrict__ out, int n4) {
    int i = blockIdx.x * blockDim.x + threadIdx.x;
    int stride = gridDim.x * blockDim.x;
    for (; i < n4; i += stride) {
        float4 v = ((const float4*)in)[i];
        ushort4 o;
        o.x = f2bf(v.x); o.y = f2bf(v.y); o.z = f2bf(v.z); o.w = f2bf(v.w);
        ((ushort4*)out)[i] = o;
    }
}

// ---------------- GRU layer scan ----------------
// 256 blocks x 64 threads (1 wave, 1 block/CU). Block owns batch rows
// r0..r0+16 (row-group rg) x h-cols c0..c0+16. Row-groups are fully
// independent streams with their own 64-block flag barrier.
// FULLZ=true  (layer 0): r,z,n weights fully LDS-resident (147KB).
// FULLZ=false (layer 1): r,n full + z h-part in LDS (160KB); z x-part
//                        streamed from L2 during the hideable x-phase.
template <int DIN, bool FULLZ>
__global__ __launch_bounds__(64, 1) void gru_scan(
    const unsigned short* __restrict__ xseq,  // [T][B][DIN] bf16
    const unsigned short* __restrict__ wih,   // [3H][DIN] bf16 (r,z,n)
    const unsigned short* __restrict__ whh,   // [3H][H]  bf16
    const float* __restrict__ bih, const float* __restrict__ bhh,
    const float* __restrict__ h0,             // [B][H] fp32
    unsigned short* __restrict__ hbuf,        // [2][B][H] bf16 (coherent exchange)
    unsigned short* __restrict__ Y,           // [T][B][H] bf16
    int* __restrict__ flags)                  // [4 rg][64 blk * 16 ints]
{
    extern __shared__ unsigned short lds[];
    constexpr int KT = D_H + DIN;

    const int lane = threadIdx.x;
    const int bid  = blockIdx.x;
    // Default dispatch round-robins XCDs by blockIdx (perf heuristic only;
    // correctness is mapping-independent). Concentrate each rg on 2 XCDs so
    // its x-slab stays in 2 L2s.
    const int xcd = bid & 7;
    const int rg  = xcd >> 1;                  // 0..3
    const int cb  = ((bid >> 3) << 1) | (xcd & 1);  // 0..63
    const int c0  = cb * 16, r0 = rg * 16;

    int* const frg   = flags + rg * 1024;      // this rg's 64 flags (16-int spaced)
    int* const myflg = frg + cb * 16;

    // ---- stage gate weights into LDS (once) ----
    const int NG = FULLZ ? 3 : 2;
    for (int g = 0; g < NG; ++g) {
        const int grow = (g == 0) ? 2 * D_H : (g == 1 ? 0 : D_H);  // n, r, z
        unsigned short* W = lds + g * 16 * KT;
        for (int i = lane; i < 16 * (D_H / 8); i += 64) {
            int c = i >> 7, kb = i & 127;
            int el = (c * KT + kb * 8) ^ ((c & 7) << 3);
            *(short8*)&W[el] = *(const short8*)&whh[(size_t)(grow + c0 + c) * D_H + kb * 8];
        }
        for (int i = lane; i < 16 * (DIN / 8); i += 64) {
            int c = i / (DIN / 8), kb = i % (DIN / 8);
            int el = (c * KT + D_H + kb * 8) ^ ((c & 7) << 3);
            *(short8*)&W[el] = *(const short8*)&wih[(size_t)(grow + c0 + c) * DIN + kb * 8];
        }
    }
    if (!FULLZ) {
        // z gate, h-part only: [16][D_H] at slot 2 (row stride D_H)
        for (int i = lane; i < 16 * (D_H / 8); i += 64) {
            int c = i >> 7, kb = i & 127;
            int el = 32 * KT + ((c * D_H + kb * 8) ^ ((c & 7) << 3));
            *(short8*)&lds[el] = *(const short8*)&whh[(size_t)(D_H + c0 + c) * D_H + kb * 8];
        }
    }
    __syncthreads();

    // ---- init h tile: fp32 state in registers, bf16 published ----
    const int gc   = c0 + (lane & 15);
    const int crow = (lane >> 4) * 4;
    float hprev[4];
    #pragma unroll
    for (int i = 0; i < 4; ++i) {
        float v = h0[(size_t)(r0 + crow + i) * D_H + gc];
        hprev[i] = v;
        store_u16_sc01(&hbuf[(size_t)(r0 + crow + i) * D_H + gc], (unsigned)f2bf(v));
    }
    asm volatile("s_waitcnt vmcnt(0)" ::: "memory");
    if (lane == 0) store_flag(myflg, 1);

    const float b_r  = bih[gc] + bhh[gc];
    const float b_z  = bih[D_H + gc] + bhh[D_H + gc];
    const float b_xn = bih[2 * D_H + gc];
    const float b_hn = bhh[2 * D_H + gc];

    const int arow = lane & 15;          // A row / B col for MFMA fragments
    const int ako  = (lane >> 4) * 8;    // k sub-offset
    const int swz  = (arow & 7) << 3;

    for (int t = 0; t < T_SEQ; ++t) {
        const unsigned short* hb  = hbuf + (t & 1) * (BATCH * D_H);
        unsigned short*       hbn = hbuf + ((t & 1) ^ 1) * (BATCH * D_H);
        const unsigned short* xt  = xseq + (size_t)t * BATCH * DIN;
        unsigned short*       Yt  = Y + (size_t)t * BATCH * D_H;

        f32x4 fr = {0.f, 0.f, 0.f, 0.f}, fz = fr, fnx = fr, fnh = fr;

        // ---- x-phase (independent of h(t); hides barrier detection) ----
        #pragma unroll 4
        for (int k = 0; k < DIN; k += 32) {
            short8 a  = *(const short8*)&xt[(size_t)(r0 + arow) * DIN + k + ako];
            int el    = (arow * KT + D_H + k + ako) ^ swz;
            short8 bn = *(const short8*)&lds[el];
            short8 br = *(const short8*)&lds[16 * KT + el];
            short8 bz;
            if (FULLZ) bz = *(const short8*)&lds[32 * KT + el];
            else       bz = *(const short8*)&wih[(size_t)(D_H + c0 + arow) * DIN + k + ako];
            fr  = __builtin_amdgcn_mfma_f32_16x16x32_bf16(a, br, fr, 0, 0, 0);
            fz  = __builtin_amdgcn_mfma_f32_16x16x32_bf16(a, bz, fz, 0, 0, 0);
            fnx = __builtin_amdgcn_mfma_f32_16x16x32_bf16(a, bn, fnx, 0, 0, 0);
        }

        // ---- flag barrier: h(t) published by all 64 rg-blocks? ----
        {
            const int p = t + 1;
            const int* fp = frg + lane * 16;
            while (true) {
                int f = load_flag(fp);
                if (__all(f >= p)) break;
            }
        }

        // ---- h fragments: direct L3 -> registers (no LDS round trip) ----
        short8 hfrag[32];
        const unsigned short* hrow = hb + (size_t)(r0 + arow) * D_H + ako;
        #pragma unroll
        for (int kk = 0; kk < 32; ++kk)
            hfrag[kk] = load16_sc01(hrow + kk * 32);
        asm volatile("s_waitcnt vmcnt(0)" ::: "memory");
        __builtin_amdgcn_sched_barrier(0);

        // ---- h-phase: all B-operands from LDS ----
        #pragma unroll
        for (int kk = 0; kk < 32; ++kk) {
            const int k = kk * 32;
            int el    = (arow * KT + k + ako) ^ swz;
            short8 bn = *(const short8*)&lds[el];
            short8 br = *(const short8*)&lds[16 * KT + el];
            int zel   = FULLZ ? (32 * KT + el)
                              : (32 * KT + ((arow * D_H + k + ako) ^ swz));
            short8 bz = *(const short8*)&lds[zel];
            fr  = __builtin_amdgcn_mfma_f32_16x16x32_bf16(hfrag[kk], br, fr, 0, 0, 0);
            fz  = __builtin_amdgcn_mfma_f32_16x16x32_bf16(hfrag[kk], bz, fz, 0, 0, 0);
            fnh = __builtin_amdgcn_mfma_f32_16x16x32_bf16(hfrag[kk], bn, fnh, 0, 0, 0);
        }

        // ---- epilogue: gates + state update; publish h(t+1) ----
        #pragma unroll
        for (int i = 0; i < 4; ++i) {
            int rr = r0 + crow + i;
            float r = fast_sigmoid(fr[i] + b_r);
            float z = fast_sigmoid(fz[i] + b_z);
            float n = fast_tanh(fnx[i] + b_xn + r * (fnh[i] + b_hn));
            float hn = (1.f - z) * n + z * hprev[i];
            hprev[i] = hn;
            unsigned short h16 = f2bf(hn);
            store_u16_sc01(&hbn[(size_t)rr * D_H + gc], (unsigned)h16);
            Yt[(size_t)rr * D_H + gc] = h16;   // normal cached store
        }
        asm volatile("s_waitcnt vmcnt(0)" ::: "memory");
        if (lane == 0) store_flag(myflg, t + 2);
    }
}

// ---------------- fused LayerNorm + output projection ----------------
__global__ __launch_bounds__(256) void ln_proj(
    const unsigned short* __restrict__ y1,   // [TB][1024] bf16
    const float* __restrict__ gamma, const float* __restrict__ beta,
    const unsigned short* __restrict__ ffw,  // [512][1024] bf16
    const float* __restrict__ ffb,           // [512]
    float* __restrict__ out)                 // [TB][512]
{
    __shared__ unsigned short ylds[16 * 1024];
    const int row0 = blockIdx.x * 16;
    const int tid = threadIdx.x;

    {
        const int rr = tid >> 4, l16 = tid & 15;
        const unsigned short* yrow = y1 + (size_t)(row0 + rr) * D_H;
        float s = 0.f, sq = 0.f;
        #pragma unroll
        for (int j8 = 0; j8 < 8; ++j8) {
            int k = l16 * 64 + j8 * 8;
            short8 v = *(const short8*)&yrow[k];
            int idx = (rr * 1024 + k) ^ ((rr & 7) << 3);
            *(short8*)&ylds[idx] = v;
            #pragma unroll
            for (int j = 0; j < 8; ++j) {
                float f = bf2f((unsigned short)v[j]);
                s += f; sq += f * f;
            }
        }
        #pragma unroll
        for (int o = 1; o < 16; o <<= 1) {
            s  += __shfl_xor(s, o, 64);
            sq += __shfl_xor(sq, o, 64);
        }
        float mu = s * (1.f / 1024.f);
        float var = sq * (1.f / 1024.f) - mu * mu;
        float rstd = rsqrtf(var + 1e-5f);
        #pragma unroll
        for (int j8 = 0; j8 < 8; ++j8) {
            int k = l16 * 64 + j8 * 8;
            int idx = (rr * 1024 + k) ^ ((rr & 7) << 3);
            short8 v = *(short8*)&ylds[idx];
            short8 o8;
            #pragma unroll
            for (int j = 0; j < 8; ++j) {
                float f = bf2f((unsigned short)v[j]);
                f = (f - mu) * rstd * gamma[k + j] + beta[k + j];
                o8[j] = (short)f2bf(f);
            }
            *(short8*)&ylds[idx] = o8;
        }
    }
    __syncthreads();

    const int w = tid >> 6, lane = tid & 63;
    const int cbase = w * 128;
    const int arow = lane & 15, ako = (lane >> 4) * 8;
    f32x4 acc[8] = {};
    for (int k = 0; k < D_H; k += 32) {
        int aidx = (arow * 1024 + k + ako) ^ ((arow & 7) << 3);
        short8 a = *(const short8*)&ylds[aidx];
        #pragma unroll
        for (int n = 0; n < 8; ++n) {
            int col = cbase + n * 16 + (lane & 15);
            short8 b = *(const short8*)&ffw[col * 1024 + k + ako];
            acc[n] = __builtin_amdgcn_mfma_f32_16x16x32_bf16(a, b, acc[n], 0, 0, 0);
        }
    }
    #pragma unroll
    for (int n = 0; n < 8; ++n) {
        int col = cbase + n * 16 + (lane & 15);
        float bb = ffb[col];
        #pragma unroll
        for (int i = 0; i < 4; ++i) {
            int rr = row0 + (lane >> 4) * 4 + i;
            out[(size_t)rr * D_OUT + col] = acc[n][i] + bb;
        }
    }
}

// ---------------- launch ----------------
extern "C" void kernel_launch(void* const* d_in, const int* in_sizes, int n_in,
                              void* d_out, int out_size, void* d_ws, size_t ws_size,
                              hipStream_t stream) {
    const float* x     = (const float*)d_in[0];
    const float* h     = (const float*)d_in[1];
    const float* w_ih0 = (const float*)d_in[2];
    const float* w_hh0 = (const float*)d_in[3];
    const float* b_ih0 = (const float*)d_in[4];
    const float* b_hh0 = (const float*)d_in[5];
    const float* w_ih1 = (const float*)d_in[6];
    const float* w_hh1 = (const float*)d_in[7];
    const float* b_ih1 = (const float*)d_in[8];
    const float* b_hh1 = (const float*)d_in[9];
    const float* ln_g  = (const float*)d_in[10];
    const float* ln_b  = (const float*)d_in[11];
    const float* ff_w  = (const float*)d_in[12];
    const float* ff_b  = (const float*)d_in[13];
    float* out = (float*)d_out;

    char* ws = (char*)d_ws;
    size_t off = 0;
    auto alloc = [&](size_t bytes) {
        void* p = ws + off;
        off = (off + bytes + 255) & ~(size_t)255;
        return p;
    };
    unsigned short* x_bf   = (unsigned short*)alloc((size_t)T_SEQ * BATCH * DIN0 * 2);
    unsigned short* y1_bf  = (unsigned short*)alloc((size_t)T_SEQ * BATCH * D_H * 2);
    unsigned short* wih0_b = (unsigned short*)alloc((size_t)3 * D_H * DIN0 * 2);
    unsigned short* whh0_b = (unsigned short*)alloc((size_t)3 * D_H * D_H * 2);
    unsigned short* wih1_b = (unsigned short*)alloc((size_t)3 * D_H * D_H * 2);
    unsigned short* whh1_b = (unsigned short*)alloc((size_t)3 * D_H * D_H * 2);
    unsigned short* ffw_b  = (unsigned short*)alloc((size_t)D_OUT * D_H * 2);
    unsigned short* hbuf   = (unsigned short*)alloc((size_t)2 * BATCH * D_H * 2);
    int*            flags  = (int*)alloc(2 * 4096 * 4);   // 2 layers x 4 rg x 64 x 16 ints
    if (off > ws_size) return;

    unsigned short* y0_bf = (unsigned short*)d_out;  // 67MB staging, overwritten by ln_proj

    hipMemsetAsync(flags, 0, 2 * 4096 * 4, stream);

    auto castl = [&](const float* src, unsigned short* dst, int n) {
        int n4 = n / 4;
        int blocks = (n4 + 255) / 256;
        if (blocks > 2048) blocks = 2048;
        hipLaunchKernelGGL(cast_kernel, dim3(blocks), dim3(256), 0, stream, src, dst, n4);
    };
    castl(x,     x_bf,   T_SEQ * BATCH * DIN0);
    castl(w_ih0, wih0_b, 3 * D_H * DIN0);
    castl(w_hh0, whh0_b, 3 * D_H * D_H);
    castl(w_ih1, wih1_b, 3 * D_H * D_H);
    castl(w_hh1, whh1_b, 3 * D_H * D_H);
    castl(ff_w,  ffw_b,  D_OUT * D_H);

    const int lds0 = 48 * (D_H + DIN0) * 2;              // 147456 (r,z,n full)
    const int lds1 = 32 * (D_H + D_H) * 2 + 16 * D_H * 2; // 163840 (r,n full + z h-part)
    hipFuncSetAttribute((const void*)&gru_scan<DIN0, true>,
                        hipFuncAttributeMaxDynamicSharedMemorySize, lds0);
    hipFuncSetAttribute((const void*)&gru_scan<D_H, false>,
                        hipFuncAttributeMaxDynamicSharedMemorySize, lds1);

    hipLaunchKernelGGL((gru_scan<DIN0, true>), dim3(NBLK), dim3(64), lds0, stream,
        x_bf, wih0_b, whh0_b, b_ih0, b_hh0, h, hbuf, y0_bf, flags);
    hipLaunchKernelGGL((gru_scan<D_H, false>), dim3(NBLK), dim3(64), lds1, stream,
        y0_bf, wih1_b, whh1_b, b_ih1, b_hh1, h + BATCH * D_H, hbuf, y1_bf,
        flags + 4096);
    hipLaunchKernelGGL(ln_proj, dim3(T_SEQ * BATCH / 16), dim3(256), 0, stream,
        y1_bf, ln_g, ln_b, ffw_b, ff_b, out);
}

// Round 5
// 8205.358 us; speedup vs baseline: 3.4910x; 1.0130x over previous
//
#include <hip/hip_runtime.h>

#define T_SEQ 512
#define BATCH 64
#define DIN0  512
#define D_H   1024
#define D_OUT 512
#define NBLK  256

typedef __attribute__((ext_vector_type(8))) short short8;
typedef __attribute__((ext_vector_type(4))) float f32x4;

__device__ inline float bf2f(unsigned short u) {
    unsigned x = ((unsigned)u) << 16;
    return __builtin_bit_cast(float, x);
}
__device__ inline unsigned short f2bf(float f) {
    unsigned x = __builtin_bit_cast(unsigned, f);
    unsigned r = (x + 0x7fffu + ((x >> 16) & 1u)) >> 16;
    return (unsigned short)r;
}
__device__ inline float fast_sigmoid(float x) { return 1.f / (1.f + __expf(-x)); }
__device__ inline float fast_tanh(float x) {
    float ax = fabsf(x);
    float t = __expf(-2.f * ax);
    float r = (1.f - t) / (1.f + t);
    return copysignf(r, x);
}

// ---- coherence-point primitives (proven rounds 2/4) ----
// global->LDS async copy, sc0|sc1 (=17): reads at L3 coherence point.
__device__ inline void async_ld16_cohere(const void* g, void* l) {
    __builtin_amdgcn_global_load_lds((const __attribute__((address_space(1))) void*)g,
                                     (__attribute__((address_space(3))) void*)l,
                                     16, 0, 17);
}
// write-through 2B store (device-visible once vmcnt==0)
__device__ inline void store_u16_sc01(void* p, unsigned v) {
    asm volatile("global_store_short %0, %1, off sc0 sc1" :: "v"(p), "v"(v) : "memory");
}
// coherence-point 16B load, no wait (batched)
__device__ inline short8 load16_sc01(const void* p) {
    short8 r;
    asm volatile("global_load_dwordx4 %0, %1, off sc0 sc1"
                 : "=&v"(r) : "v"(p) : "memory");
    return r;
}
// coherence-point 16B load with wait (poll)
__device__ inline short8 load16_sc01_wait(const void* p) {
    short8 r;
    asm volatile("global_load_dwordx4 %0, %1, off sc0 sc1\n\ts_waitcnt vmcnt(0)"
                 : "=&v"(r) : "v"(p) : "memory");
    return r;
}

// ---------------- cast fp32 -> bf16 ----------------
__global__ void cast_kernel(const float* __restrict__ in, unsigned short* __restrict__ out, int n4) {
    int i = blockIdx.x * blockDim.x + threadIdx.x;
    int stride = gridDim.x * blockDim.x;
    for (; i < n4; i += stride) {
        float4 v = ((const float4*)in)[i];
        ushort4 o;
        o.x = f2bf(v.x); o.y = f2bf(v.y); o.z = f2bf(v.z); o.w = f2bf(v.w);
        ((ushort4*)out)[i] = o;
    }
}

// ---------------- GRU layer scan (producer/consumer waves) ----------------
// 256 blocks x 128 threads (2 waves, 1 block/CU, 160KB LDS).
// Block (rg,cb): batch rows rg*16..+16, h-cols cb*16..+16.
// wave0 = compute: x-phase || (wave1: poll+fetch h into LDS) -> sync -> h-phase
// wave1 = sync: packed-flag poll + coherent global_load_lds of the h slab.
// LDS (ushort elems): stage[16*1024] @0 ; WHn @16384 ; WHr @32768 ;
//   FULLZH: WHz @49152, WX @65536   else: WX @49152 (z fully streamed).
template <int DIN, bool FULLZH>
__global__ __launch_bounds__(128, 1) void gru_scan(
    const unsigned short* __restrict__ xseq,  // [T][B][DIN] bf16
    const unsigned short* __restrict__ wih,   // [3H][DIN] bf16 (r,z,n)
    const unsigned short* __restrict__ whh,   // [3H][H]  bf16
    const float* __restrict__ bih, const float* __restrict__ bhh,
    const float* __restrict__ h0,             // [B][H] fp32
    unsigned short* __restrict__ hbuf,        // [2][B][H] bf16 (coherent exchange)
    unsigned short* __restrict__ Y,           // [T][B][H] bf16
    unsigned short* __restrict__ flags)       // [4 rg][64] ushort, 128B/rg
{
    extern __shared__ unsigned short lds[];
    constexpr int WX_BASE = FULLZH ? 65536 : 49152;

    const int tid  = threadIdx.x;
    const int lane = tid & 63;
    const int wv   = tid >> 6;
    const int bid  = blockIdx.x;
    const int xcd  = bid & 7;
    const int rg   = xcd >> 1;                      // 0..3 (rg pinned to 2 XCDs)
    const int cb   = ((bid >> 3) << 1) | (xcd & 1); // 0..63
    const int c0   = cb * 16, r0 = rg * 16;

    unsigned short* const frg = flags + rg * 64;

    // ---- stage weights into LDS (both waves, 128 threads) ----
    {
        const int NG = FULLZH ? 3 : 2;
        for (int g = 0; g < NG; ++g) {
            const int grow = (g == 0) ? 2 * D_H : (g == 1 ? 0 : D_H);  // n, r, z
            unsigned short* W = lds + 16384 + g * 16384;
            for (int i = tid; i < 16 * 128; i += 128) {
                int c = i >> 7, kb = i & 127;
                int el = (c * 1024 + kb * 8) ^ ((c & 7) << 3);
                *(short8*)&W[el] = *(const short8*)&whh[(size_t)(grow + c0 + c) * D_H + kb * 8];
            }
        }
        for (int g = 0; g < 2; ++g) {
            const int grow = (g == 0) ? 2 * D_H : 0;   // n, r
            unsigned short* W = lds + WX_BASE + g * 16 * DIN;
            for (int i = tid; i < 16 * (DIN / 8); i += 128) {
                int c = i / (DIN / 8), kb = i % (DIN / 8);
                int el = (c * DIN + kb * 8) ^ ((c & 7) << 3);
                *(short8*)&W[el] = *(const short8*)&wih[(size_t)(grow + c0 + c) * DIN + kb * 8];
            }
        }
    }
    __syncthreads();

    // ---- wave0: init h tile (fp32 state in regs), publish, flag=1 ----
    const int gc   = c0 + (lane & 15);
    const int crow = (lane >> 4) * 4;
    float hprev[4];
    float b_r, b_z, b_xn, b_hn;
    if (wv == 0) {
        #pragma unroll
        for (int i = 0; i < 4; ++i) {
            float v = h0[(size_t)(r0 + crow + i) * D_H + gc];
            hprev[i] = v;
            store_u16_sc01(&hbuf[(size_t)(r0 + crow + i) * D_H + gc], (unsigned)f2bf(v));
        }
        asm volatile("s_waitcnt vmcnt(0)" ::: "memory");
        if (lane == 0) store_u16_sc01(&frg[cb], 1u);
        b_r  = bih[gc] + bhh[gc];
        b_z  = bih[D_H + gc] + bhh[D_H + gc];
        b_xn = bih[2 * D_H + gc];
        b_hn = bhh[2 * D_H + gc];
    }

    const int arow = lane & 15;          // A row / B col for MFMA fragments
    const int ako  = (lane >> 4) * 8;    // k sub-offset
    const int swz  = (arow & 7) << 3;

    f32x4 fr, fz, fnx, fnh;

    for (int t = 0; t < T_SEQ; ++t) {
        const unsigned short* hb  = hbuf + (t & 1) * (BATCH * D_H);
        unsigned short*       hbn = hbuf + ((t & 1) ^ 1) * (BATCH * D_H);
        const unsigned short* xt  = xseq + (size_t)t * BATCH * DIN;
        unsigned short*       Yt  = Y + (size_t)t * BATCH * D_H;

        if (wv == 1) {
            // ---- sync wave: poll packed flags, then fetch h slab into LDS ----
            const int p = t + 1;
            const unsigned short* fp = frg + (lane & 7) * 8;
            while (true) {
                short8 f = load16_sc01_wait(fp);
                bool ok = true;
                #pragma unroll
                for (int j = 0; j < 8; ++j)
                    ok &= ((unsigned short)f[j] >= (unsigned)p);
                if (__all(ok)) break;
            }
            #pragma unroll
            for (int i = 0; i < 32; ++i) {
                int row = i >> 1, hf = i & 1;
                int sw8 = row & 7;
                const unsigned short* src =
                    hb + (size_t)(r0 + row) * D_H + (hf * 64 + (lane ^ sw8)) * 8;
                async_ld16_cohere(src, &lds[row * 1024 + hf * 512]);
            }
            asm volatile("s_waitcnt vmcnt(0)" ::: "memory");
        } else {
            // ---- compute wave: x-phase (independent of h(t)) ----
            fr = (f32x4){0.f, 0.f, 0.f, 0.f}; fz = fr; fnx = fr; fnh = fr;
            #pragma unroll 4
            for (int k = 0; k < DIN; k += 32) {
                short8 a  = *(const short8*)&xt[(size_t)(r0 + arow) * DIN + k + ako];
                int el    = (arow * DIN + k + ako) ^ swz;
                short8 bn = *(const short8*)&lds[WX_BASE + el];
                short8 br = *(const short8*)&lds[WX_BASE + 16 * DIN + el];
                short8 bz = *(const short8*)&wih[(size_t)(D_H + c0 + arow) * DIN + k + ako];
                fr  = __builtin_amdgcn_mfma_f32_16x16x32_bf16(a, br, fr, 0, 0, 0);
                fz  = __builtin_amdgcn_mfma_f32_16x16x32_bf16(a, bz, fz, 0, 0, 0);
                fnx = __builtin_amdgcn_mfma_f32_16x16x32_bf16(a, bn, fnx, 0, 0, 0);
            }
        }
        __syncthreads();   // stage holds h(t); wave0 done with x-phase

        if (wv == 0) {
            // ---- h-phase: A from LDS stage, B(n,r) from LDS, z per FULLZH ----
            #pragma unroll 4
            for (int k = 0; k < D_H; k += 32) {
                int sel   = (arow * 1024 + k + ako) ^ swz;
                short8 a  = *(const short8*)&lds[sel];
                int el    = (arow * 1024 + k + ako) ^ swz;
                short8 bn = *(const short8*)&lds[16384 + el];
                short8 br = *(const short8*)&lds[32768 + el];
                short8 bz;
                if (FULLZH) bz = *(const short8*)&lds[49152 + el];
                else        bz = *(const short8*)&whh[(size_t)(D_H + c0 + arow) * D_H + k + ako];
                fr  = __builtin_amdgcn_mfma_f32_16x16x32_bf16(a, br, fr, 0, 0, 0);
                fz  = __builtin_amdgcn_mfma_f32_16x16x32_bf16(a, bz, fz, 0, 0, 0);
                fnh = __builtin_amdgcn_mfma_f32_16x16x32_bf16(a, bn, fnh, 0, 0, 0);
            }

            // ---- epilogue: gates, state update; publish h fast, flag, then Y ----
            unsigned short h16[4];
            #pragma unroll
            for (int i = 0; i < 4; ++i) {
                int rr = r0 + crow + i;
                float r = fast_sigmoid(fr[i] + b_r);
                float z = fast_sigmoid(fz[i] + b_z);
                float n = fast_tanh(fnx[i] + b_xn + r * (fnh[i] + b_hn));
                float hn = (1.f - z) * n + z * hprev[i];
                hprev[i] = hn;
                h16[i] = f2bf(hn);
                store_u16_sc01(&hbn[(size_t)rr * D_H + gc], (unsigned)h16[i]);
            }
            asm volatile("s_waitcnt vmcnt(0)" ::: "memory");
            if (lane == 0) store_u16_sc01(&frg[cb], (unsigned)(t + 2));
            #pragma unroll
            for (int i = 0; i < 4; ++i)
                Yt[(size_t)(r0 + crow + i) * D_H + gc] = h16[i];
        }
        __syncthreads();   // wave0 done reading stage; wave1 may overwrite next iter
    }
}

// ---------------- fused LayerNorm + output projection ----------------
__global__ __launch_bounds__(256) void ln_proj(
    const unsigned short* __restrict__ y1,   // [TB][1024] bf16
    const float* __restrict__ gamma, const float* __restrict__ beta,
    const unsigned short* __restrict__ ffw,  // [512][1024] bf16
    const float* __restrict__ ffb,           // [512]
    float* __restrict__ out)                 // [TB][512]
{
    __shared__ unsigned short ylds[16 * 1024];
    const int row0 = blockIdx.x * 16;
    const int tid = threadIdx.x;

    {
        const int rr = tid >> 4, l16 = tid & 15;
        const unsigned short* yrow = y1 + (size_t)(row0 + rr) * D_H;
        float s = 0.f, sq = 0.f;
        #pragma unroll
        for (int j8 = 0; j8 < 8; ++j8) {
            int k = l16 * 64 + j8 * 8;
            short8 v = *(const short8*)&yrow[k];
            int idx = (rr * 1024 + k) ^ ((rr & 7) << 3);
            *(short8*)&ylds[idx] = v;
            #pragma unroll
            for (int j = 0; j < 8; ++j) {
                float f = bf2f((unsigned short)v[j]);
                s += f; sq += f * f;
            }
        }
        #pragma unroll
        for (int o = 1; o < 16; o <<= 1) {
            s  += __shfl_xor(s, o, 64);
            sq += __shfl_xor(sq, o, 64);
        }
        float mu = s * (1.f / 1024.f);
        float var = sq * (1.f / 1024.f) - mu * mu;
        float rstd = rsqrtf(var + 1e-5f);
        #pragma unroll
        for (int j8 = 0; j8 < 8; ++j8) {
            int k = l16 * 64 + j8 * 8;
            int idx = (rr * 1024 + k) ^ ((rr & 7) << 3);
            short8 v = *(short8*)&ylds[idx];
            short8 o8;
            #pragma unroll
            for (int j = 0; j < 8; ++j) {
                float f = bf2f((unsigned short)v[j]);
                f = (f - mu) * rstd * gamma[k + j] + beta[k + j];
                o8[j] = (short)f2bf(f);
            }
            *(short8*)&ylds[idx] = o8;
        }
    }
    __syncthreads();

    const int w = tid >> 6, lane = tid & 63;
    const int cbase = w * 128;
    const int arow = lane & 15, ako = (lane >> 4) * 8;
    f32x4 acc[8] = {};
    for (int k = 0; k < D_H; k += 32) {
        int aidx = (arow * 1024 + k + ako) ^ ((arow & 7) << 3);
        short8 a = *(const short8*)&ylds[aidx];
        #pragma unroll
        for (int n = 0; n < 8; ++n) {
            int col = cbase + n * 16 + (lane & 15);
            short8 b = *(const short8*)&ffw[col * 1024 + k + ako];
            acc[n] = __builtin_amdgcn_mfma_f32_16x16x32_bf16(a, b, acc[n], 0, 0, 0);
        }
    }
    #pragma unroll
    for (int n = 0; n < 8; ++n) {
        int col = cbase + n * 16 + (lane & 15);
        float bb = ffb[col];
        #pragma unroll
        for (int i = 0; i < 4; ++i) {
            int rr = row0 + (lane >> 4) * 4 + i;
            out[(size_t)rr * D_OUT + col] = acc[n][i] + bb;
        }
    }
}

// ---------------- launch ----------------
extern "C" void kernel_launch(void* const* d_in, const int* in_sizes, int n_in,
                              void* d_out, int out_size, void* d_ws, size_t ws_size,
                              hipStream_t stream) {
    const float* x     = (const float*)d_in[0];
    const float* h     = (const float*)d_in[1];
    const float* w_ih0 = (const float*)d_in[2];
    const float* w_hh0 = (const float*)d_in[3];
    const float* b_ih0 = (const float*)d_in[4];
    const float* b_hh0 = (const float*)d_in[5];
    const float* w_ih1 = (const float*)d_in[6];
    const float* w_hh1 = (const float*)d_in[7];
    const float* b_ih1 = (const float*)d_in[8];
    const float* b_hh1 = (const float*)d_in[9];
    const float* ln_g  = (const float*)d_in[10];
    const float* ln_b  = (const float*)d_in[11];
    const float* ff_w  = (const float*)d_in[12];
    const float* ff_b  = (const float*)d_in[13];
    float* out = (float*)d_out;

    char* ws = (char*)d_ws;
    size_t off = 0;
    auto alloc = [&](size_t bytes) {
        void* p = ws + off;
        off = (off + bytes + 255) & ~(size_t)255;
        return p;
    };
    unsigned short* x_bf   = (unsigned short*)alloc((size_t)T_SEQ * BATCH * DIN0 * 2);
    unsigned short* y1_bf  = (unsigned short*)alloc((size_t)T_SEQ * BATCH * D_H * 2);
    unsigned short* wih0_b = (unsigned short*)alloc((size_t)3 * D_H * DIN0 * 2);
    unsigned short* whh0_b = (unsigned short*)alloc((size_t)3 * D_H * D_H * 2);
    unsigned short* wih1_b = (unsigned short*)alloc((size_t)3 * D_H * D_H * 2);
    unsigned short* whh1_b = (unsigned short*)alloc((size_t)3 * D_H * D_H * 2);
    unsigned short* ffw_b  = (unsigned short*)alloc((size_t)D_OUT * D_H * 2);
    unsigned short* hbuf   = (unsigned short*)alloc((size_t)2 * BATCH * D_H * 2);
    unsigned short* flags  = (unsigned short*)alloc(2 * 4 * 64 * 2);   // 2 layers x 4rg x 64
    if (off > ws_size) return;

    unsigned short* y0_bf = (unsigned short*)d_out;  // 67MB staging, overwritten by ln_proj

    hipMemsetAsync(flags, 0, 2 * 4 * 64 * 2, stream);

    auto castl = [&](const float* src, unsigned short* dst, int n) {
        int n4 = n / 4;
        int blocks = (n4 + 255) / 256;
        if (blocks > 2048) blocks = 2048;
        hipLaunchKernelGGL(cast_kernel, dim3(blocks), dim3(256), 0, stream, src, dst, n4);
    };
    castl(x,     x_bf,   T_SEQ * BATCH * DIN0);
    castl(w_ih0, wih0_b, 3 * D_H * DIN0);
    castl(w_hh0, whh0_b, 3 * D_H * D_H);
    castl(w_ih1, wih1_b, 3 * D_H * D_H);
    castl(w_hh1, whh1_b, 3 * D_H * D_H);
    castl(ff_w,  ffw_b,  D_OUT * D_H);

    const int ldsb = 163840;   // both layers: exactly 160KB
    hipFuncSetAttribute((const void*)&gru_scan<DIN0, true>,
                        hipFuncAttributeMaxDynamicSharedMemorySize, ldsb);
    hipFuncSetAttribute((const void*)&gru_scan<D_H, false>,
                        hipFuncAttributeMaxDynamicSharedMemorySize, ldsb);

    hipLaunchKernelGGL((gru_scan<DIN0, true>), dim3(NBLK), dim3(128), ldsb, stream,
        x_bf, wih0_b, whh0_b, b_ih0, b_hh0, h, hbuf, y0_bf, flags);
    hipLaunchKernelGGL((gru_scan<D_H, false>), dim3(NBLK), dim3(128), ldsb, stream,
        y0_bf, wih1_b, whh1_b, b_ih1, b_hh1, h + BATCH * D_H, hbuf, y1_bf,
        flags + 256);
    hipLaunchKernelGGL(ln_proj, dim3(T_SEQ * BATCH / 16), dim3(256), 0, stream,
        y1_bf, ln_g, ln_b, ffw_b, ff_b, out);
}